// Round 9
// baseline (272.329 us; speedup 1.0000x reference)
//
#include <hip/hip_runtime.h>

// ---------------- problem constants ----------------
#define BATCH     16
#define T_LEN     480000
#define PAD       512
#define TPAD      481024      // T_LEN + 2*PAD
#define HOP       256
#define NFRAMES   1876        // (TPAD - NFFT)/HOP + 1
#define NOUTROW   1026        // 513 freqs * 2 (re,im interleaved)
#define KTOT      1024
#define BCOLS     1024        // bmat rows: freqs 0..511 re/im. f=512 -> f512_col.
#define XPSTRIDE  493568      // proven xp row stride

// ---------------- GEMM tile config ----------------
#define BM        256         // frames per block
#define BN        128         // cols per block (8 j-tiles cover 1024 real cols)
#define BK        32
#define NTILES    32
#define ABUF      16384       // A: 4 kq x 256 rows x 16B chunks
#define BBUF      8192        // B: 4 kq x 128 cols x 16B chunks
#define BUFB      (ABUF + BBUF)   // 24576; x2 dbuf = 48 KB -> 2 blocks/CU

typedef __attribute__((ext_vector_type(8))) short short8;
typedef __attribute__((ext_vector_type(4))) float floatx4;

#define GPTR(p) (const __attribute__((address_space(1))) void*)(p)
#define LPTR(p) (__attribute__((address_space(3))) void*)(p)

__device__ __forceinline__ unsigned short f2bf(float f) {
  union { float f; unsigned int u; } v; v.f = f;
  unsigned int u = v.u;
  return (unsigned short)((u + 0x7FFFu + ((u >> 16) & 1u)) >> 16); // RNE
}

// Reflect-padded signal as bf16, row stride XPSTRIDE, tail zero-filled.
__global__ __launch_bounds__(256) void build_xp(const float* __restrict__ x,
                                                unsigned short* __restrict__ xp) {
  const int i0 = (blockIdx.x * 256 + threadIdx.x) * 8;
  const int b  = blockIdx.y;
  const float* xb = x + (size_t)b * T_LEN;
  const int j0 = i0 - PAD;
  union { short8 v; unsigned short u[8]; } o;
  if (j0 >= 0 && j0 + 8 <= T_LEN) {
    const float4 lo = *(const float4*)(xb + j0);
    const float4 hi = *(const float4*)(xb + j0 + 4);
    o.u[0] = f2bf(lo.x); o.u[1] = f2bf(lo.y); o.u[2] = f2bf(lo.z); o.u[3] = f2bf(lo.w);
    o.u[4] = f2bf(hi.x); o.u[5] = f2bf(hi.y); o.u[6] = f2bf(hi.z); o.u[7] = f2bf(hi.w);
  } else {
#pragma unroll
    for (int e = 0; e < 8; ++e) {
      const int i = i0 + e;
      unsigned short v = 0;
      if (i < TPAD) {
        int j = i - PAD;
        if (j < 0) j = -j;
        if (j >= T_LEN) j = 2 * T_LEN - 2 - j;
        v = f2bf(xb[j]);
      }
      o.u[e] = v;
    }
  }
  *(short8*)(xp + (size_t)b * XPSTRIDE + i0) = o.v;
}

// Basis bmat[j][k], j in [0,1024): 2f -> cos(2pi f k/1024)*w, 2f+1 -> -sin*w.
__global__ __launch_bounds__(256) void build_bmat(const float* __restrict__ win,
                                                  unsigned short* __restrict__ bm) {
  const int id = blockIdx.x * 256 + threadIdx.x;   // [0, 1024*128)
  const int j  = id >> 7;
  const int k0 = (id & 127) * 8;
  const int f  = j >> 1;
  const float4 w0 = *(const float4*)(win + k0);
  const float4 w1 = *(const float4*)(win + k0 + 4);
  const float wv[8] = {w0.x, w0.y, w0.z, w0.w, w1.x, w1.y, w1.z, w1.w};
  union { short8 v; unsigned short u[8]; } o;
#pragma unroll
  for (int e = 0; e < 8; ++e) {
    const int r = (f * (k0 + e)) & (KTOT - 1);     // exact arg reduction
    const float ang = (float)r * 6.1359231515e-3f; // 2*pi/1024
    const float c = __cosf(ang), s = __sinf(ang);
    o.u[e] = f2bf(((j & 1) ? -s : c) * wv[e]);
  }
  *(short8*)(bm + (size_t)j * KTOT + k0) = o.v;
}

// Output cols 1024/1025 (f=512): basis is (-1)^k * w[k] and exactly 0.
// One wave per frame: lane l sums k = l+64j (sign = (-1)^l), shuffle-reduce.
__global__ __launch_bounds__(256) void f512_col(const unsigned short* __restrict__ xp,
                                                const float* __restrict__ win,
                                                float* __restrict__ out) {
  const int t = blockIdx.x * 4 + (threadIdx.x >> 6);   // 469*4 = 1876 exact
  const int b = blockIdx.y;
  const int l = threadIdx.x & 63;
  const unsigned short* xw = xp + (size_t)b * XPSTRIDE + (size_t)t * HOP;
  float s = 0.f;
#pragma unroll
  for (int j = 0; j < 16; ++j) {
    const int k = j * 64 + l;
    union { unsigned int u; float f; } cv;
    cv.u = (unsigned int)xw[k] << 16;
    s += win[k] * cv.f;
  }
  if (l & 1) s = -s;
#pragma unroll
  for (int off = 32; off > 0; off >>= 1) s += __shfl_down(s, off, 64);
  if (l == 0)
    *(float2*)(out + (size_t)(b * NFRAMES + t) * NOUTROW + 1024) = make_float2(s, 0.f);
}

// C[m][j] = sum_k xp[b][t*HOP+k] * bmat[j][k].  256 thr / 4 waves (2M x 2N),
// wave tile 128x64 (round-8 verified fragment math).  A+B double-buffered in
// 48 KB LDS -> 2 blocks/CU (stall overlap).  Per K-tile: issue 6 global_load_lds
// for tile T+1 at the top (full tile of latency cover), 32 MFMAs on tile T,
// ONE __syncthreads (its vmcnt(0) drain is covered; lgkm consumed by MFMAs).
// LDS layout [kq][row] -> lane-consecutive 16B frag reads (0 conflicts, r8).
__global__ __launch_bounds__(256, 2) void stft_gemm(const unsigned short* __restrict__ xp,
                                                    const unsigned short* __restrict__ bmat,
                                                    float* __restrict__ out) {
  __shared__ char smem[2 * BUFB];

  const int tid  = threadIdx.x;            // 0..255
  const int lane = tid & 63;
  const int wv   = tid >> 6;               // 0..3
  const int wm   = wv >> 1;                // 0..1 : M 128-slice
  const int wn   = wv & 1;                 // 0..1 : N 64-slice
  const int L    = lane & 15;
  const int quad = lane >> 4;
  const int b    = blockIdx.x >> 3;
  const int t0   = (blockIdx.x & 7) * BM;  // frame base, <=1792
  const int j0   = blockIdx.y * BN;        // 0..896 step 128

  // Staging sources. A: thread owns row=tid, kq=p (4 loads); tail M-tile rows
  // >=1876 read past the xp row into defined workspace (garbage feeds only
  // never-stored frames; MFMA rows are independent).  B: chunk ci=p*256+tid
  // -> col=tid&127, kq=2p+(tid>>7) (2 loads); max read = bmat's last byte.
  const unsigned short* asrc = xp + (size_t)b * XPSTRIDE + (size_t)(t0 + tid) * HOP;
  const int col = tid & 127;
  const int kqb = tid >> 7;
  const unsigned short* bsrc0 = bmat + (size_t)(j0 + col) * KTOT + kqb * 8;
  const unsigned short* bsrc1 = bmat + (size_t)(j0 + col) * KTOT + (2 + kqb) * 8;

#define STAGE(T1, NB)                                                          \
  {                                                                            \
    const int ko_ = (T1) * BK;                                                 \
    _Pragma("unroll") for (int p = 0; p < 4; ++p)                              \
      __builtin_amdgcn_global_load_lds(GPTR(asrc + ko_ + p * 8),               \
          LPTR((NB) + (p * 256 + tid) * 16), 16, 0, 0);                        \
    __builtin_amdgcn_global_load_lds(GPTR(bsrc0 + ko_),                        \
        LPTR((NB) + ABUF + tid * 16), 16, 0, 0);                               \
    __builtin_amdgcn_global_load_lds(GPTR(bsrc1 + ko_),                        \
        LPTR((NB) + ABUF + (256 + tid) * 16), 16, 0, 0);                       \
  }

  // Fragment byte offsets within a buffer (round-8 verified mapping):
  // af[mf]: chunk = quad*256 + wm*128 + mf*16 + L ; bf[n]: quad*128+wn*64+n*16+L
  const int aof = (quad * 256 + wm * 128 + L) * 16;
  const int bof = ABUF + (quad * 128 + wn * 64 + L) * 16;

  floatx4 acc[8][4] = {};

  // ---- prologue: stage tile 0 into buf0 ----
  STAGE(0, (char*)smem);
  __syncthreads();

  for (int T = 0; T < NTILES; ++T) {
    const char* cb = (const char*)smem + (T & 1) * BUFB;
    char* nb = (char*)smem + ((T + 1) & 1) * BUFB;
    if (T + 1 < NTILES) STAGE(T + 1, nb);   // uniform branch

    short8 af[4], bf[4];
#pragma unroll
    for (int n = 0; n < 4; ++n) bf[n] = *(const short8*)(cb + bof + n * 256);
#pragma unroll
    for (int m = 0; m < 4; ++m) af[m] = *(const short8*)(cb + aof + m * 256);
    __builtin_amdgcn_s_setprio(1);
#pragma unroll
    for (int m = 0; m < 4; ++m)
#pragma unroll
      for (int n = 0; n < 4; ++n)
        acc[m][n] = __builtin_amdgcn_mfma_f32_16x16x32_bf16(
            af[m], bf[n], acc[m][n], 0, 0, 0);
    __builtin_amdgcn_s_setprio(0);
#pragma unroll
    for (int m = 0; m < 4; ++m) af[m] = *(const short8*)(cb + aof + (m + 4) * 256);
    __builtin_amdgcn_s_setprio(1);
#pragma unroll
    for (int m = 0; m < 4; ++m)
#pragma unroll
      for (int n = 0; n < 4; ++n)
        acc[m + 4][n] = __builtin_amdgcn_mfma_f32_16x16x32_bf16(
            af[m], bf[n], acc[m + 4][n], 0, 0, 0);
    __builtin_amdgcn_s_setprio(0);

    __syncthreads();   // vmcnt(0) drain covered by a full tile of compute
  }

  // ---- epilogue: D[row = quad*4 + i][col = L] per 16x16 tile ----
#pragma unroll
  for (int mf = 0; mf < 8; ++mf) {
    const int tb = t0 + wm * 128 + mf * 16 + quad * 4;
#pragma unroll
    for (int n = 0; n < 4; ++n) {
      const int gj = j0 + wn * 64 + n * 16 + L;   // always < 1024: no guard
#pragma unroll
      for (int i = 0; i < 4; ++i) {
        const int t = tb + i;
        if (t < NFRAMES)
          out[(size_t)(b * NFRAMES + t) * NOUTROW + gj] = acc[mf][n][i];
      }
    }
  }
}

extern "C" void kernel_launch(void* const* d_in, const int* in_sizes, int n_in,
                              void* d_out, int out_size, void* d_ws, size_t ws_size,
                              hipStream_t stream) {
  const float* x   = (const float*)d_in[0];   // (16, 480000) fp32
  const float* win = (const float*)d_in[1];   // (1024,) fp32
  float* out = (float*)d_out;                 // (16, 1876, 513, 2) fp32

  unsigned short* xp   = (unsigned short*)d_ws;                  // 15.79 MB
  unsigned short* bmat = xp + (size_t)BATCH * XPSTRIDE;          // 2.00 MB

  build_xp  <<<dim3(XPSTRIDE / 2048, BATCH), 256, 0, stream>>>(x, xp);
  build_bmat<<<dim3(BCOLS * (KTOT / 8) / 256), 256, 0, stream>>>(win, bmat);
  stft_gemm <<<dim3(BATCH * 8, BCOLS / BN), 256, 0, stream>>>(xp, bmat, out);
  f512_col  <<<dim3(NFRAMES / 4, BATCH), 256, 0, stream>>>(xp, win, out);
}